// Round 10
// baseline (83.275 us; speedup 1.0000x reference)
//
#include <hip/hip_runtime.h>

#define BATCH 8
#define ROWS  2048
#define WIDTH 4096
#define COLS  4096
#define KB    1024   // WIDTH/4 gating blocks along k
#define CBV   1024   // COLS/4  float4s per W row
#define ZPART 32     // row-chunks per batch (partials)
#define RCH   64     // ROWS / ZPART
#define NDOT  256    // dot-kernel blocks (z x k-chunk)

typedef float f32x4 __attribute__((ext_vector_type(4)));

// ---------------------------------------------------------------------------
// Fused kernel, 2048 blocks, parity-interleaved so both streams co-reside:
//   even bid (1024): colsum — part[z][b][k] = sum_{r in chunk z} X[b,r,k]
//   odd  bid (1024): gate   — wg[b, 4kb+j] = sum_c W[4kb+j, c] * G[b, kb, c/4]
// Gate reduction uses a fold-butterfly: 32 shfls/wave (was 192).
// ---------------------------------------------------------------------------
__global__ __launch_bounds__(256) void fused_kernel(const f32x4* __restrict__ X,
                                                    const f32x4* __restrict__ Wv,
                                                    const f32x4* __restrict__ Gv,
                                                    f32x4* __restrict__ part,
                                                    float* __restrict__ wg) {
    const int t = threadIdx.x;
    if (!(blockIdx.x & 1)) {
        // ---------------- colsum: strip pattern (proven) --------------------
        const int s  = blockIdx.x >> 1;     // [0, 1024)
        const int k4 = (s & 3) * 256 + t;   // [0, 1024)
        const int b  = (s >> 2) & 7;
        const int z  = s >> 5;              // [0, 32)

        const f32x4* p = X + (size_t)(b * ROWS + z * RCH) * (WIDTH / 4) + k4;
        f32x4 a = {0.f, 0.f, 0.f, 0.f};
#pragma unroll 8
        for (int r = 0; r < RCH; ++r) {
            f32x4 v = p[(size_t)r * (WIDTH / 4)];
            a.x += v.x; a.y += v.y; a.z += v.z; a.w += v.w;
        }
        part[((size_t)(z * BATCH + b) << 10) + k4] = a;
    } else {
        // ---------------- gate: one block per kb ----------------------------
        const int kb = blockIdx.x >> 1;     // [0, 1024)
        const int lane = t & 63, wv = t >> 6;

        f32x4 w[4][4];  // [j][m]: W[4kb+j, 4*(4t+m) .. +3]
#pragma unroll
        for (int j = 0; j < 4; ++j)
#pragma unroll
            for (int m = 0; m < 4; ++m)
                w[j][m] = Wv[(size_t)(4 * kb + j) * CBV + 4 * t + m];

        f32x4 g[8];     // G[b, kb, 4t..4t+3]
#pragma unroll
        for (int b = 0; b < 8; ++b)
            g[b] = Gv[((size_t)(b * KB + kb) << 8) + t];

        float w4[4][4];  // 4-col block sums of W
#pragma unroll
        for (int j = 0; j < 4; ++j)
#pragma unroll
            for (int m = 0; m < 4; ++m)
                w4[j][m] = (w[j][m].x + w[j][m].y) + (w[j][m].z + w[j][m].w);

        // vals[v], v = (b<<2)|j — per-thread gated partial for (b, 4kb+j)
        float vals[32];
#pragma unroll
        for (int v = 0; v < 32; ++v) {
            const int b = v >> 2, j = v & 3;
            vals[v] = g[b].x * w4[j][0] + g[b].y * w4[j][1] +
                      g[b].z * w4[j][2] + g[b].w * w4[j][3];
        }

        // fold-butterfly: 5 steps; each lane ends with one fully-reduced
        // value (index = bitrev5(lane&31)); 31 shfls, all-static indexing.
#pragma unroll
        for (int s = 0; s < 5; ++s) {
            const int o = 1 << s;
            const int h = 16 >> s;
            const bool hi = (lane & o) != 0;
#pragma unroll
            for (int i = 0; i < h; ++i) {
                float keep = hi ? vals[h + i] : vals[i];
                float send = hi ? vals[i] : vals[h + i];
                vals[i] = keep + __shfl_xor(send, o, 64);
            }
        }
        float tot = vals[0] + __shfl_xor(vals[0], 32, 64);  // full 64-lane sum

        __shared__ float lds[4][32];
        if (lane < 32) lds[wv][lane] = tot;
        __syncthreads();
        if (t < 32) {
            float r = (lds[0][t] + lds[1][t]) + (lds[2][t] + lds[3][t]);
            const int v = ((t & 1) << 4) | ((t & 2) << 2) | (t & 4) |
                          ((t & 8) >> 2) | ((t & 16) >> 4);  // bitrev5
            wg[(size_t)(v >> 2) * WIDTH + 4 * kb + (v & 3)] = r;
        }
    }
}

// ---------------------------------------------------------------------------
// F1: 256 blocks — block (z = bid>>3, kc = bid&7) dots a 16 KB slice of
// part[z] against the matching wg slice (wg chunks go L2-hot).
// ---------------------------------------------------------------------------
__global__ __launch_bounds__(256) void dot_kernel(const f32x4* __restrict__ part,
                                                  const f32x4* __restrict__ wgv,
                                                  float* __restrict__ partial) {
    const int z  = blockIdx.x >> 3;  // [0, 32)
    const int kc = blockIdx.x & 7;   // [0, 8)
    const f32x4* pz = part + ((size_t)z * BATCH << 10);

    float acc = 0.f;
#pragma unroll
    for (int rep = 0; rep < 4; ++rep) {
        const int i = (kc << 10) + rep * 256 + threadIdx.x;
        f32x4 a = pz[i], b = wgv[i];
        acc += a.x * b.x + a.y * b.y + a.z * b.z + a.w * b.w;
    }
#pragma unroll
    for (int o = 1; o < 64; o <<= 1) acc += __shfl_xor(acc, o, 64);
    __shared__ float lds[4];
    const int lane = threadIdx.x & 63, wv = threadIdx.x >> 6;
    if (lane == 0) lds[wv] = acc;
    __syncthreads();
    if (threadIdx.x == 0) partial[blockIdx.x] = (lds[0] + lds[1]) + (lds[2] + lds[3]);
}

// ---------------------------------------------------------------------------
// F2: s = sum(partial[0..256)); out[0] = s*s. One 256-thread block.
// ---------------------------------------------------------------------------
__global__ __launch_bounds__(256) void square_kernel(const float* __restrict__ partial,
                                                     float* __restrict__ out) {
    float v = partial[threadIdx.x];
#pragma unroll
    for (int o = 1; o < 64; o <<= 1) v += __shfl_xor(v, o, 64);
    __shared__ float lds[4];
    const int lane = threadIdx.x & 63, wv = threadIdx.x >> 6;
    if (lane == 0) lds[wv] = v;
    __syncthreads();
    if (threadIdx.x == 0) {
        float s = (lds[0] + lds[1]) + (lds[2] + lds[3]);
        out[0] = s * s;
    }
}

extern "C" void kernel_launch(void* const* d_in, const int* in_sizes, int n_in,
                              void* d_out, int out_size, void* d_ws, size_t ws_size,
                              hipStream_t stream) {
    const float* X = (const float*)d_in[0];  // (8, 2048, 4096)
    const float* W = (const float*)d_in[1];  // (4096, 4096)
    const float* G = (const float*)d_in[2];  // (8, 1024, 1024)
    float* out = (float*)d_out;              // scalar

    float* part    = (float*)d_ws;                           // 4 MB, fully rewritten
    float* wg      = part + (size_t)ZPART * BATCH * WIDTH;   // 128 KB, fully rewritten
    float* partial = wg + (size_t)BATCH * WIDTH;             // 256 f32, fully rewritten

    fused_kernel<<<2048, 256, 0, stream>>>((const f32x4*)X, (const f32x4*)W,
                                           (const f32x4*)G, (f32x4*)part, wg);

    dot_kernel<<<NDOT, 256, 0, stream>>>((const f32x4*)part, (const f32x4*)wg, partial);

    square_kernel<<<1, 256, 0, stream>>>(partial, out);
}

// Round 11
// 81.546 us; speedup vs baseline: 1.0212x; 1.0212x over previous
//
#include <hip/hip_runtime.h>

#define BATCH 8
#define ROWS  2048
#define WIDTH 4096
#define COLS  4096
#define KB    1024   // WIDTH/4 gating blocks along k
#define CBV   1024   // COLS/4  float4s per W row
#define ZPART 32     // row-chunks per batch (partials)
#define RCH   64     // ROWS / ZPART
#define NDOT  256    // dot-kernel blocks (z x k-chunk)

typedef float f32x4 __attribute__((ext_vector_type(4)));

__device__ __forceinline__ void ntstore4(f32x4* p, f32x4 v) {
    __builtin_nontemporal_store(v, p);
}
__device__ __forceinline__ void ntstoref(float* p, float v) {
    __builtin_nontemporal_store(v, p);
}

// ---------------------------------------------------------------------------
// Fused kernel, 2048 blocks, parity-interleaved so both streams co-reside:
//   even bid (1024): colsum — part[z][b][k] = sum_{r in chunk z} X[b,r,k]
//   odd  bid (1024): gate   — wg[b, 4kb+j] = sum_c W[4kb+j, c] * G[b, kb, c/4]
// Stores are NON-TEMPORAL (stream-out, never re-read in-kernel) so they
// don't allocate L2 lines against the three read streams.
// ---------------------------------------------------------------------------
__global__ __launch_bounds__(256) void fused_kernel(const f32x4* __restrict__ X,
                                                    const f32x4* __restrict__ Wv,
                                                    const f32x4* __restrict__ Gv,
                                                    f32x4* __restrict__ part,
                                                    float* __restrict__ wg) {
    const int t = threadIdx.x;
    if (!(blockIdx.x & 1)) {
        // ---------------- colsum: strip pattern (proven) --------------------
        const int s  = blockIdx.x >> 1;     // [0, 1024)
        const int k4 = (s & 3) * 256 + t;   // [0, 1024)
        const int b  = (s >> 2) & 7;
        const int z  = s >> 5;              // [0, 32)

        const f32x4* p = X + (size_t)(b * ROWS + z * RCH) * (WIDTH / 4) + k4;
        f32x4 a = {0.f, 0.f, 0.f, 0.f};
#pragma unroll 8
        for (int r = 0; r < RCH; ++r) {
            f32x4 v = p[(size_t)r * (WIDTH / 4)];
            a.x += v.x; a.y += v.y; a.z += v.z; a.w += v.w;
        }
        ntstore4(&part[((size_t)(z * BATCH + b) << 10) + k4], a);
    } else {
        // ---------------- gate: one block per kb ----------------------------
        const int kb = blockIdx.x >> 1;     // [0, 1024)
        const int lane = t & 63, wv = t >> 6;

        f32x4 w[4][4];  // [j][m]: W[4kb+j, 4*(4t+m) .. +3]
#pragma unroll
        for (int j = 0; j < 4; ++j)
#pragma unroll
            for (int m = 0; m < 4; ++m)
                w[j][m] = Wv[(size_t)(4 * kb + j) * CBV + 4 * t + m];

        f32x4 g[8];     // G[b, kb, 4t..4t+3]
#pragma unroll
        for (int b = 0; b < 8; ++b)
            g[b] = Gv[((size_t)(b * KB + kb) << 8) + t];

        float w4[4][4];  // 4-col block sums of W
#pragma unroll
        for (int j = 0; j < 4; ++j)
#pragma unroll
            for (int m = 0; m < 4; ++m)
                w4[j][m] = (w[j][m].x + w[j][m].y) + (w[j][m].z + w[j][m].w);

        float acc[8][4];
#pragma unroll
        for (int b = 0; b < 8; ++b)
#pragma unroll
            for (int j = 0; j < 4; ++j)
                acc[b][j] = g[b].x * w4[j][0] + g[b].y * w4[j][1] +
                            g[b].z * w4[j][2] + g[b].w * w4[j][3];

        // reduce 32 accumulators (b,j) across 256 threads (R8/R9 proven form)
        __shared__ float lds[4][32];
#pragma unroll
        for (int v = 0; v < 32; ++v) {
            float x = acc[v >> 2][v & 3];
#pragma unroll
            for (int o = 1; o < 64; o <<= 1) x += __shfl_xor(x, o, 64);
            if (lane == 0) lds[wv][v] = x;
        }
        __syncthreads();
        if (t < 32) {
            float r = (lds[0][t] + lds[1][t]) + (lds[2][t] + lds[3][t]);
            ntstoref(&wg[(size_t)(t >> 2) * WIDTH + 4 * kb + (t & 3)], r);
        }
    }
}

// ---------------------------------------------------------------------------
// F1: 256 blocks — block (z = bid>>3, kc = bid&7) dots a 16 KB slice of
// part[z] against the matching wg slice (wg chunks go L2-hot).
// ---------------------------------------------------------------------------
__global__ __launch_bounds__(256) void dot_kernel(const f32x4* __restrict__ part,
                                                  const f32x4* __restrict__ wgv,
                                                  float* __restrict__ partial) {
    const int z  = blockIdx.x >> 3;  // [0, 32)
    const int kc = blockIdx.x & 7;   // [0, 8)
    const f32x4* pz = part + ((size_t)z * BATCH << 10);

    float acc = 0.f;
#pragma unroll
    for (int rep = 0; rep < 4; ++rep) {
        const int i = (kc << 10) + rep * 256 + threadIdx.x;
        f32x4 a = pz[i], b = wgv[i];
        acc += a.x * b.x + a.y * b.y + a.z * b.z + a.w * b.w;
    }
#pragma unroll
    for (int o = 1; o < 64; o <<= 1) acc += __shfl_xor(acc, o, 64);
    __shared__ float lds[4];
    const int lane = threadIdx.x & 63, wv = threadIdx.x >> 6;
    if (lane == 0) lds[wv] = acc;
    __syncthreads();
    if (threadIdx.x == 0)
        ntstoref(&partial[blockIdx.x], (lds[0] + lds[1]) + (lds[2] + lds[3]));
}

// ---------------------------------------------------------------------------
// F2: s = sum(partial[0..256)); out[0] = s*s. One 256-thread block.
// ---------------------------------------------------------------------------
__global__ __launch_bounds__(256) void square_kernel(const float* __restrict__ partial,
                                                     float* __restrict__ out) {
    float v = partial[threadIdx.x];
#pragma unroll
    for (int o = 1; o < 64; o <<= 1) v += __shfl_xor(v, o, 64);
    __shared__ float lds[4];
    const int lane = threadIdx.x & 63, wv = threadIdx.x >> 6;
    if (lane == 0) lds[wv] = v;
    __syncthreads();
    if (threadIdx.x == 0) {
        float s = (lds[0] + lds[1]) + (lds[2] + lds[3]);
        out[0] = s * s;
    }
}

extern "C" void kernel_launch(void* const* d_in, const int* in_sizes, int n_in,
                              void* d_out, int out_size, void* d_ws, size_t ws_size,
                              hipStream_t stream) {
    const float* X = (const float*)d_in[0];  // (8, 2048, 4096)
    const float* W = (const float*)d_in[1];  // (4096, 4096)
    const float* G = (const float*)d_in[2];  // (8, 1024, 1024)
    float* out = (float*)d_out;              // scalar

    float* part    = (float*)d_ws;                           // 4 MB, fully rewritten
    float* wg      = part + (size_t)ZPART * BATCH * WIDTH;   // 128 KB, fully rewritten
    float* partial = wg + (size_t)BATCH * WIDTH;             // 256 f32, fully rewritten

    fused_kernel<<<2048, 256, 0, stream>>>((const f32x4*)X, (const f32x4*)W,
                                           (const f32x4*)G, (f32x4*)part, wg);

    dot_kernel<<<NDOT, 256, 0, stream>>>((const f32x4*)part, (const f32x4*)wg, partial);

    square_kernel<<<1, 256, 0, stream>>>(partial, out);
}